// Round 1
// baseline (1378.758 us; speedup 1.0000x reference)
//
#include <hip/hip_runtime.h>
#include <math.h>

// ---------------------------------------------------------------------------
// Com_CNN_RNN R6: data-polling sync (canary = FLT_MAX bits).
//  - GRU h values satisfy |h| < 1 strictly, so 0x7F7FFFFF is unreachable.
//  - k_init poisons hbuf0/hbuf1/tb0/tb1/tr each launch (stream-ordered, so
//    graph replay is safe); consumers poll data words directly instead of
//    flags. Removes the writer-side waitcnt+barrier+flag-store and the
//    consumer-side flag-poll->data-load double round trip per step.
//  - k_pipe: double-buffered LDS staging -> single __syncthreads per step,
//    no end-of-step barrier, no flags at all.
//  - k_tail: all 6 PUBLISH/WAIT_ALL rounds replaced by data-polls; only the
//    Mmax broadcast keeps a flag (conv outputs are unbounded).
// ---------------------------------------------------------------------------

#define CANARY_U 0x7F7FFFFFu   // FLT_MAX bit pattern; |GRU h| < 1 can't hit it

__device__ __forceinline__ float sigm(float x) { return 1.f / (1.f + expf(-x)); }

// LDS index map: p(k) = k + (k>>4)*4 (pad 4 words per 16; keeps float4 align)
#define LDSP(k) ((k) + (((k) >> 4) << 2))

__device__ __forceinline__ float red32(float v) {
    v += __shfl_xor(v, 16, 64);
    v += __shfl_xor(v, 8, 64);
    v += __shfl_xor(v, 4, 64);
    v += __shfl_xor(v, 2, 64);
    v += __shfl_xor(v, 1, 64);
    return v;
}

__device__ __forceinline__ void poll_ge(const unsigned int* p, unsigned tgt) {
    unsigned v;
    do {
        v = __hip_atomic_load(p, __ATOMIC_RELAXED, __HIP_MEMORY_SCOPE_AGENT);
        if (v < tgt) __builtin_amdgcn_s_sleep(1);
    } while (v < tgt);
}

// One staging thread (i in 0..255): poll its 4 words of src until none is the
// canary, then write them to LDS. Caller barriers afterwards.
__device__ __forceinline__ void stage_poll(float* dst, const float* src, int i) {
    const unsigned long long* s = (const unsigned long long*)src + (size_t)i * 2;
    unsigned long long a, b;
    for (;;) {
        a = __hip_atomic_load(s + 0, __ATOMIC_RELAXED, __HIP_MEMORY_SCOPE_AGENT);
        b = __hip_atomic_load(s + 1, __ATOMIC_RELAXED, __HIP_MEMORY_SCOPE_AGENT);
        if ((unsigned int)a != CANARY_U && (unsigned int)(a >> 32) != CANARY_U &&
            (unsigned int)b != CANARY_U && (unsigned int)(b >> 32) != CANARY_U)
            break;
        __builtin_amdgcn_s_sleep(1);
    }
    union { unsigned long long u; float2 f; } c0, c1;
    c0.u = a; c1.u = b;
    float* d = dst + LDSP(i * 4);
    d[0] = c0.f.x; d[1] = c0.f.y; d[2] = c1.f.x; d[3] = c1.f.y;
}

__device__ __forceinline__ float gru1(float gr, float gz, float gn,
                                      float ar, float az, float an,
                                      const float bh[3], float hp) {
    float r = sigm(gr + ar + bh[0]);
    float z = sigm(gz + az + bh[1]);
    float n = tanhf(gn + r * (an + bh[2]));
    return (1.f - z) * n + z * hp;
}

// ---------------------------------------------------------------------------
// k_pipe: epoch-1 L0 + L1 pipelined, data-polling. grid 64 x 512.
// ---------------------------------------------------------------------------
__global__ __launch_bounds__(512, 1) void k_pipe(
    const float* __restrict__ Whh1, const float* __restrict__ bhh1,
    const float* __restrict__ Wih1, const float* __restrict__ bih1,
    const float* __restrict__ gi0,        // [2][256][1536] (L0 only)
    float* __restrict__ e2x,              // [2 sent][2 layer][512]
    float* __restrict__ hbuf0,            // [257][2][512] poisoned t=1..256
    float* __restrict__ hbuf1)            // [257][2][512] poisoned t=1..256
{
    const int tid   = threadIdx.x;
    const int layer = blockIdx.x >> 5;    // 0 or 1
    const int wgi   = blockIdx.x & 31;
    const int grp   = tid >> 5;           // 0..15
    const int lane  = tid & 31;
    const int j     = wgi * 16 + grp;     // h row 0..511
    const int colbase = lane * 16;

    __shared__ float xlds[2][1280];
    __shared__ float hlds[2][1280];

    const size_t WS = (size_t)1536 * 512;
    const float* WH = Whh1 + (size_t)layer * WS;

    // recurrent weights resident
    float wh[3][16];
#pragma unroll
    for (int q = 0; q < 3; ++q) {
        const float* src = WH + (size_t)(q * 512 + j) * 512 + colbase;
#pragma unroll
        for (int c4 = 0; c4 < 4; ++c4) {
            float4 v = *(const float4*)(src + c4 * 4);
            wh[q][c4*4+0] = v.x; wh[q][c4*4+1] = v.y;
            wh[q][c4*4+2] = v.z; wh[q][c4*4+3] = v.w;
        }
    }
#pragma unroll
    for (int q = 0; q < 3; ++q)
#pragma unroll
        for (int c = 0; c < 16; ++c)
            asm volatile("" : "+v"(wh[q][c]));

    float bh[3];
#pragma unroll
    for (int q = 0; q < 3; ++q) bh[q] = bhh1[layer * 1536 + q * 512 + j];

    float hprev[2] = {0.f, 0.f};
    int buf = 0;

    if (layer == 0) {
        // ------------------------- L0 -------------------------
        for (int t = 1; t <= 256; ++t) {
            float g0[3][2];
#pragma unroll
            for (int q = 0; q < 3; ++q)
#pragma unroll
                for (int s = 0; s < 2; ++s)
                    g0[q][s] = gi0[((size_t)(s * 256 + t - 1)) * 1536 + q * 512 + j];

            float acc[3][2] = {{0.f,0.f},{0.f,0.f},{0.f,0.f}};
            if (t > 1) {
                if (tid < 256)
                    stage_poll(xlds[buf], hbuf0 + (size_t)(t - 1) * 1024, tid);
                __syncthreads();
#pragma unroll
                for (int s = 0; s < 2; ++s) {
                    const int base = s * 640 + 20 * lane;
#pragma unroll
                    for (int c4 = 0; c4 < 4; ++c4) {
                        float4 hv = *(const float4*)&xlds[buf][base + c4 * 4];
#pragma unroll
                        for (int q = 0; q < 3; ++q)
                            acc[q][s] += wh[q][c4*4+0]*hv.x + wh[q][c4*4+1]*hv.y
                                       + wh[q][c4*4+2]*hv.z + wh[q][c4*4+3]*hv.w;
                    }
                }
#pragma unroll
                for (int q = 0; q < 3; ++q)
#pragma unroll
                    for (int s = 0; s < 2; ++s) acc[q][s] = red32(acc[q][s]);
            }

            float hn[2];
#pragma unroll
            for (int s = 0; s < 2; ++s) {
                hn[s] = gru1(g0[0][s], g0[1][s], g0[2][s],
                             acc[0][s], acc[1][s], acc[2][s], bh, hprev[s]);
                hprev[s] = hn[s];
            }
            if (lane == 0) {
#pragma unroll
                for (int s = 0; s < 2; ++s) {
                    __hip_atomic_store(hbuf0 + (size_t)t * 1024 + s * 512 + j, hn[s],
                                       __ATOMIC_RELAXED, __HIP_MEMORY_SCOPE_AGENT);
                    if (t == 256) e2x[s * 1024 + j] = hn[s];
                }
            }
            buf ^= 1;
        }
    } else {
        // ------------------------- L1 (skewed by 1 step) -------------------------
        const float* WI = Wih1 + WS;
        float wi[3][16];
#pragma unroll
        for (int q = 0; q < 3; ++q) {
            const float* src = WI + (size_t)(q * 512 + j) * 512 + colbase;
#pragma unroll
            for (int c4 = 0; c4 < 4; ++c4) {
                float4 v = *(const float4*)(src + c4 * 4);
                wi[q][c4*4+0] = v.x; wi[q][c4*4+1] = v.y;
                wi[q][c4*4+2] = v.z; wi[q][c4*4+3] = v.w;
            }
        }
#pragma unroll
        for (int q = 0; q < 3; ++q)
#pragma unroll
            for (int c = 0; c < 16; ++c)
                asm volatile("" : "+v"(wi[q][c]));

        float bi[3];
#pragma unroll
        for (int q = 0; q < 3; ++q) bi[q] = bih1[1536 + q * 512 + j];

        for (int t = 1; t <= 256; ++t) {
            if (tid < 256)
                stage_poll(xlds[buf], hbuf0 + (size_t)t * 1024, tid);
            else if (t > 1)
                stage_poll(hlds[buf], hbuf1 + (size_t)(t - 1) * 1024, tid - 256);
            __syncthreads();

            // combined accumulators: r,z get gi+gh summed; n kept separate
            float aR[2] = {0.f,0.f}, aZ[2] = {0.f,0.f};
            float aGN[2] = {0.f,0.f}, aHN[2] = {0.f,0.f};
#pragma unroll
            for (int s = 0; s < 2; ++s) {
                const int base = s * 640 + 20 * lane;
#pragma unroll
                for (int c4 = 0; c4 < 4; ++c4) {
                    float4 xv = *(const float4*)&xlds[buf][base + c4 * 4];
                    aR[s]  += wi[0][c4*4+0]*xv.x + wi[0][c4*4+1]*xv.y
                            + wi[0][c4*4+2]*xv.z + wi[0][c4*4+3]*xv.w;
                    aZ[s]  += wi[1][c4*4+0]*xv.x + wi[1][c4*4+1]*xv.y
                            + wi[1][c4*4+2]*xv.z + wi[1][c4*4+3]*xv.w;
                    aGN[s] += wi[2][c4*4+0]*xv.x + wi[2][c4*4+1]*xv.y
                            + wi[2][c4*4+2]*xv.z + wi[2][c4*4+3]*xv.w;
                }
                if (t > 1) {
#pragma unroll
                    for (int c4 = 0; c4 < 4; ++c4) {
                        float4 hv = *(const float4*)&hlds[buf][base + c4 * 4];
                        aR[s]  += wh[0][c4*4+0]*hv.x + wh[0][c4*4+1]*hv.y
                                + wh[0][c4*4+2]*hv.z + wh[0][c4*4+3]*hv.w;
                        aZ[s]  += wh[1][c4*4+0]*hv.x + wh[1][c4*4+1]*hv.y
                                + wh[1][c4*4+2]*hv.z + wh[1][c4*4+3]*hv.w;
                        aHN[s] += wh[2][c4*4+0]*hv.x + wh[2][c4*4+1]*hv.y
                                + wh[2][c4*4+2]*hv.z + wh[2][c4*4+3]*hv.w;
                    }
                }
            }
#pragma unroll
            for (int s = 0; s < 2; ++s) {
                aR[s] = red32(aR[s]); aZ[s] = red32(aZ[s]);
                aGN[s] = red32(aGN[s]); aHN[s] = red32(aHN[s]);
            }

            float hn[2];
#pragma unroll
            for (int s = 0; s < 2; ++s) {
                float r = sigm(aR[s] + bi[0] + bh[0]);
                float z = sigm(aZ[s] + bi[1] + bh[1]);
                float n = tanhf(aGN[s] + bi[2] + r * (aHN[s] + bh[2]));
                hn[s] = (1.f - z) * n + z * hprev[s];
                hprev[s] = hn[s];
            }
            if (lane == 0) {
#pragma unroll
                for (int s = 0; s < 2; ++s) {
                    __hip_atomic_store(hbuf1 + (size_t)t * 1024 + s * 512 + j, hn[s],
                                       __ATOMIC_RELAXED, __HIP_MEMORY_SCOPE_AGENT);
                    if (t == 256) e2x[s * 1024 + 512 + j] = hn[s];
                }
            }
            buf ^= 1;
        }
    }
}

// ---------------------------------------------------------------------------
// k_tail: e2-L0 -> e2-L1 -> conv+pool -> rnn2 -> head, data-polling. 32 x 512.
// ---------------------------------------------------------------------------
__global__ __launch_bounds__(512, 1) void k_tail(
    const float* __restrict__ Wih1, const float* __restrict__ bih1,
    const float* __restrict__ Whh1, const float* __restrict__ bhh1,
    const float* __restrict__ convw, const float* __restrict__ convb,
    const float* __restrict__ Whh2, const float* __restrict__ bhh2,
    const float* __restrict__ bih2, const float* __restrict__ Srow,
    const float* __restrict__ e2x,
    const float* __restrict__ WA, const float* __restrict__ WB,
    const float* __restrict__ b_bi, const float* __restrict__ Wlin,
    const float* __restrict__ blin,
    float* __restrict__ tb0, float* __restrict__ tb1, float* __restrict__ tr,
    float* __restrict__ Mmax, unsigned int* __restrict__ mf,
    float* __restrict__ outp)
{
    const int tid = threadIdx.x;
    const int wgi = blockIdx.x;
    const int grp = tid >> 5, lane = tid & 31;
    const int j = wgi * 16 + grp, colbase = lane * 16;
    const size_t WS = (size_t)1536 * 512;

    __shared__ float xlds[1280];
    __shared__ float hlds[1280];
    __shared__ float red[8];
    __shared__ float smax[4];

    // -------- stage e2x into LDS (plain loads; written by previous dispatch)
    if (tid < 256) {
        const int i = tid * 4, s = i >> 9, k = i & 511;
        float4 v = *(const float4*)(e2x + s * 1024 + k);        // timestep 0
        float* d = xlds + LDSP(i);
        d[0] = v.x; d[1] = v.y; d[2] = v.z; d[3] = v.w;
    } else {
        const int i = (tid - 256) * 4, s = i >> 9, k = i & 511;
        float4 v = *(const float4*)(e2x + s * 1024 + 512 + k);  // timestep 1
        float* d = hlds + LDSP(i);
        d[0] = v.x; d[1] = v.y; d[2] = v.z; d[3] = v.w;
    }
    __syncthreads();

    // ================= stage A: e2-L0 =================
    float gp[2][2][3];   // [t][s][q]
    float bh[3], hp[2];
#pragma unroll
    for (int q = 0; q < 3; ++q) {
        const float* wp = Wih1 + (size_t)(q * 512 + j) * 512 + colbase;
        float w16[16];
#pragma unroll
        for (int c4 = 0; c4 < 4; ++c4) {
            float4 v = *(const float4*)(wp + c4 * 4);
            w16[c4*4+0] = v.x; w16[c4*4+1] = v.y; w16[c4*4+2] = v.z; w16[c4*4+3] = v.w;
        }
        float d00 = 0.f, d01 = 0.f, d10 = 0.f, d11 = 0.f;
#pragma unroll
        for (int c4 = 0; c4 < 4; ++c4) {
            float4 x0 = *(const float4*)&xlds[0 * 640 + 20 * lane + c4 * 4];
            float4 x1 = *(const float4*)&xlds[1 * 640 + 20 * lane + c4 * 4];
            float4 y0 = *(const float4*)&hlds[0 * 640 + 20 * lane + c4 * 4];
            float4 y1 = *(const float4*)&hlds[1 * 640 + 20 * lane + c4 * 4];
            d00 += w16[c4*4+0]*x0.x + w16[c4*4+1]*x0.y + w16[c4*4+2]*x0.z + w16[c4*4+3]*x0.w;
            d01 += w16[c4*4+0]*x1.x + w16[c4*4+1]*x1.y + w16[c4*4+2]*x1.z + w16[c4*4+3]*x1.w;
            d10 += w16[c4*4+0]*y0.x + w16[c4*4+1]*y0.y + w16[c4*4+2]*y0.z + w16[c4*4+3]*y0.w;
            d11 += w16[c4*4+0]*y1.x + w16[c4*4+1]*y1.y + w16[c4*4+2]*y1.z + w16[c4*4+3]*y1.w;
        }
        const float biq = bih1[q * 512 + j];
        gp[0][0][q] = red32(d00) + biq; gp[0][1][q] = red32(d01) + biq;
        gp[1][0][q] = red32(d10) + biq; gp[1][1][q] = red32(d11) + biq;
    }
#pragma unroll
    for (int q = 0; q < 3; ++q) bh[q] = bhh1[q * 512 + j];

    // step 1 (h0 = 0)
#pragma unroll
    for (int s = 0; s < 2; ++s)
        hp[s] = gru1(gp[0][s][0], gp[0][s][1], gp[0][s][2], 0.f, 0.f, 0.f, bh, 0.f);
    if (lane == 0)
#pragma unroll
        for (int s = 0; s < 2; ++s)
            __hip_atomic_store(tb0 + 1024 + s * 512 + j, hp[s],
                               __ATOMIC_RELAXED, __HIP_MEMORY_SCOPE_AGENT);

    // step 2
    __syncthreads();                       // gp reads of xlds/hlds done
    if (tid < 256) stage_poll(hlds, tb0 + 1024, tid);
    __syncthreads();
    {
        float wh3[3][16];
#pragma unroll
        for (int q = 0; q < 3; ++q) {
            const float* wp = Whh1 + (size_t)(q * 512 + j) * 512 + colbase;
#pragma unroll
            for (int c4 = 0; c4 < 4; ++c4) {
                float4 v = *(const float4*)(wp + c4 * 4);
                wh3[q][c4*4+0] = v.x; wh3[q][c4*4+1] = v.y;
                wh3[q][c4*4+2] = v.z; wh3[q][c4*4+3] = v.w;
            }
        }
        float acc[3][2] = {{0.f,0.f},{0.f,0.f},{0.f,0.f}};
#pragma unroll
        for (int s = 0; s < 2; ++s) {
            const int base = s * 640 + 20 * lane;
#pragma unroll
            for (int c4 = 0; c4 < 4; ++c4) {
                float4 hv = *(const float4*)&hlds[base + c4 * 4];
#pragma unroll
                for (int q = 0; q < 3; ++q)
                    acc[q][s] += wh3[q][c4*4+0]*hv.x + wh3[q][c4*4+1]*hv.y
                               + wh3[q][c4*4+2]*hv.z + wh3[q][c4*4+3]*hv.w;
            }
        }
#pragma unroll
        for (int s = 0; s < 2; ++s) {
            float a0 = red32(acc[0][s]), a1 = red32(acc[1][s]), a2 = red32(acc[2][s]);
            hp[s] = gru1(gp[1][s][0], gp[1][s][1], gp[1][s][2], a0, a1, a2, bh, hp[s]);
        }
        if (lane == 0)
#pragma unroll
            for (int s = 0; s < 2; ++s)
                __hip_atomic_store(tb0 + 2048 + s * 512 + j, hp[s],
                                   __ATOMIC_RELAXED, __HIP_MEMORY_SCOPE_AGENT);
    }

    // ================= stage B: e2-L1 =================
    __syncthreads();                       // step-2 reads of hlds done
    if (tid < 256) stage_poll(xlds, tb0 + 1024, tid);      // x step0 = L0 h1
    else           stage_poll(hlds, tb0 + 2048, tid - 256); // x step1 = L0 h2
    __syncthreads();
#pragma unroll
    for (int q = 0; q < 3; ++q) {
        const float* wp = Wih1 + WS + (size_t)(q * 512 + j) * 512 + colbase;
        float w16[16];
#pragma unroll
        for (int c4 = 0; c4 < 4; ++c4) {
            float4 v = *(const float4*)(wp + c4 * 4);
            w16[c4*4+0] = v.x; w16[c4*4+1] = v.y; w16[c4*4+2] = v.z; w16[c4*4+3] = v.w;
        }
        float d00 = 0.f, d01 = 0.f, d10 = 0.f, d11 = 0.f;
#pragma unroll
        for (int c4 = 0; c4 < 4; ++c4) {
            float4 x0 = *(const float4*)&xlds[0 * 640 + 20 * lane + c4 * 4];
            float4 x1 = *(const float4*)&xlds[1 * 640 + 20 * lane + c4 * 4];
            float4 y0 = *(const float4*)&hlds[0 * 640 + 20 * lane + c4 * 4];
            float4 y1 = *(const float4*)&hlds[1 * 640 + 20 * lane + c4 * 4];
            d00 += w16[c4*4+0]*x0.x + w16[c4*4+1]*x0.y + w16[c4*4+2]*x0.z + w16[c4*4+3]*x0.w;
            d01 += w16[c4*4+0]*x1.x + w16[c4*4+1]*x1.y + w16[c4*4+2]*x1.z + w16[c4*4+3]*x1.w;
            d10 += w16[c4*4+0]*y0.x + w16[c4*4+1]*y0.y + w16[c4*4+2]*y0.z + w16[c4*4+3]*y0.w;
            d11 += w16[c4*4+0]*y1.x + w16[c4*4+1]*y1.y + w16[c4*4+2]*y1.z + w16[c4*4+3]*y1.w;
        }
        const float biq = bih1[1536 + q * 512 + j];
        gp[0][0][q] = red32(d00) + biq; gp[0][1][q] = red32(d01) + biq;
        gp[1][0][q] = red32(d10) + biq; gp[1][1][q] = red32(d11) + biq;
    }
#pragma unroll
    for (int q = 0; q < 3; ++q) bh[q] = bhh1[1536 + q * 512 + j];

#pragma unroll
    for (int s = 0; s < 2; ++s)
        hp[s] = gru1(gp[0][s][0], gp[0][s][1], gp[0][s][2], 0.f, 0.f, 0.f, bh, 0.f);
    if (lane == 0)
#pragma unroll
        for (int s = 0; s < 2; ++s)
            __hip_atomic_store(tb1 + 1024 + s * 512 + j, hp[s],
                               __ATOMIC_RELAXED, __HIP_MEMORY_SCOPE_AGENT);

    __syncthreads();                       // gp reads of hlds done
    if (tid < 256) stage_poll(hlds, tb1 + 1024, tid);
    __syncthreads();
    {
        float wh3[3][16];
#pragma unroll
        for (int q = 0; q < 3; ++q) {
            const float* wp = Whh1 + WS + (size_t)(q * 512 + j) * 512 + colbase;
#pragma unroll
            for (int c4 = 0; c4 < 4; ++c4) {
                float4 v = *(const float4*)(wp + c4 * 4);
                wh3[q][c4*4+0] = v.x; wh3[q][c4*4+1] = v.y;
                wh3[q][c4*4+2] = v.z; wh3[q][c4*4+3] = v.w;
            }
        }
        float acc[3][2] = {{0.f,0.f},{0.f,0.f},{0.f,0.f}};
#pragma unroll
        for (int s = 0; s < 2; ++s) {
            const int base = s * 640 + 20 * lane;
#pragma unroll
            for (int c4 = 0; c4 < 4; ++c4) {
                float4 hv = *(const float4*)&hlds[base + c4 * 4];
#pragma unroll
                for (int q = 0; q < 3; ++q)
                    acc[q][s] += wh3[q][c4*4+0]*hv.x + wh3[q][c4*4+1]*hv.y
                               + wh3[q][c4*4+2]*hv.z + wh3[q][c4*4+3]*hv.w;
            }
        }
#pragma unroll
        for (int s = 0; s < 2; ++s) {
            float a0 = red32(acc[0][s]), a1 = red32(acc[1][s]), a2 = red32(acc[2][s]);
            hp[s] = gru1(gp[1][s][0], gp[1][s][1], gp[1][s][2], a0, a1, a2, bh, hp[s]);
        }
        if (lane == 0)
#pragma unroll
            for (int s = 0; s < 2; ++s)
                __hip_atomic_store(tb1 + 2048 + s * 512 + j, hp[s],
                                   __ATOMIC_RELAXED, __HIP_MEMORY_SCOPE_AGENT);
    }

    // ================= stage C: conv + global max pool =================
    __syncthreads();                       // stage-B reads of xlds/hlds done
    float m4[4];
    if (wgi == 0) {
        if (tid < 256) stage_poll(xlds, tb0 + 2048, tid);       // finals L0
        else           stage_poll(hlds, tb1 + 2048, tid - 256); // finals L1
        __syncthreads();
        for (int so = 0; so < 4; ++so) {
            const int s = so >> 1, o = so & 1;
            float acc = -3.4e38f;
            if (tid < 256) {
                acc = convb[o];
                const int base = 2 * tid - 255;
                for (int k = 0; k < 512; ++k) {
                    const int pos = base + k;
                    if ((unsigned)pos < 512u) {
                        const int gi0i = s * 512 + pos;
                        acc += xlds[LDSP(gi0i)] * convw[(size_t)(o * 2 + 0) * 512 + k]
                             + hlds[LDSP(gi0i)] * convw[(size_t)(o * 2 + 1) * 512 + k];
                    }
                }
            }
            float m = acc;
            m = fmaxf(m, __shfl_xor(m, 32, 64));
            m = fmaxf(m, __shfl_xor(m, 16, 64));
            m = fmaxf(m, __shfl_xor(m, 8, 64));
            m = fmaxf(m, __shfl_xor(m, 4, 64));
            m = fmaxf(m, __shfl_xor(m, 2, 64));
            m = fmaxf(m, __shfl_xor(m, 1, 64));
            if ((tid & 63) == 0) red[tid >> 6] = m;
            __syncthreads();
            if (tid == 0) {
                float mm = red[0];
                for (int i = 1; i < 8; ++i) mm = fmaxf(mm, red[i]);
                smax[so] = mm;
            }
            __syncthreads();
        }
        if (tid == 0) {
            for (int i = 0; i < 4; ++i)
                __hip_atomic_store(Mmax + i, smax[i],
                                   __ATOMIC_RELAXED, __HIP_MEMORY_SCOPE_AGENT);
            __builtin_amdgcn_s_waitcnt(0);
            __hip_atomic_store(mf, 1u, __ATOMIC_RELAXED, __HIP_MEMORY_SCOPE_AGENT);
        }
        __syncthreads();
#pragma unroll
        for (int i = 0; i < 4; ++i) m4[i] = smax[i];
    } else {
        if (tid == 0) poll_ge(mf, 1u);
        __syncthreads();
#pragma unroll
        for (int i = 0; i < 4; ++i)
            m4[i] = __hip_atomic_load((const float*)Mmax + i, __ATOMIC_RELAXED,
                                      __HIP_MEMORY_SCOPE_AGENT);
    }

    // ================= stage D: rnn2 (T=2, gi = Mmax*Srow + bih2) =================
    {
        float wh3[3][16];
#pragma unroll
        for (int q = 0; q < 3; ++q) {
            const float* wp = Whh2 + (size_t)(q * 512 + j) * 512 + colbase;
#pragma unroll
            for (int c4 = 0; c4 < 4; ++c4) {
                float4 v = *(const float4*)(wp + c4 * 4);
                wh3[q][c4*4+0] = v.x; wh3[q][c4*4+1] = v.y;
                wh3[q][c4*4+2] = v.z; wh3[q][c4*4+3] = v.w;
            }
        }
#pragma unroll
        for (int q = 0; q < 3; ++q) {
            const float sq = Srow[q * 512 + j];
            const float biq = bih2[q * 512 + j];
#pragma unroll
            for (int s = 0; s < 2; ++s) {
                gp[0][s][q] = m4[s * 2 + 0] * sq + biq;
                gp[1][s][q] = m4[s * 2 + 1] * sq + biq;
            }
            bh[q] = bhh2[q * 512 + j];
        }
#pragma unroll
        for (int s = 0; s < 2; ++s)
            hp[s] = gru1(gp[0][s][0], gp[0][s][1], gp[0][s][2], 0.f, 0.f, 0.f, bh, 0.f);
        if (lane == 0)
#pragma unroll
            for (int s = 0; s < 2; ++s)
                __hip_atomic_store(tr + 1024 + s * 512 + j, hp[s],
                                   __ATOMIC_RELAXED, __HIP_MEMORY_SCOPE_AGENT);

        __syncthreads();                   // conv (WG0) / stage-B (others) hlds reads done
        if (tid < 256) stage_poll(hlds, tr + 1024, tid);
        __syncthreads();
        float acc[3][2] = {{0.f,0.f},{0.f,0.f},{0.f,0.f}};
#pragma unroll
        for (int s = 0; s < 2; ++s) {
            const int base = s * 640 + 20 * lane;
#pragma unroll
            for (int c4 = 0; c4 < 4; ++c4) {
                float4 hv = *(const float4*)&hlds[base + c4 * 4];
#pragma unroll
                for (int q = 0; q < 3; ++q)
                    acc[q][s] += wh3[q][c4*4+0]*hv.x + wh3[q][c4*4+1]*hv.y
                               + wh3[q][c4*4+2]*hv.z + wh3[q][c4*4+3]*hv.w;
            }
        }
#pragma unroll
        for (int s = 0; s < 2; ++s) {
            float a0 = red32(acc[0][s]), a1 = red32(acc[1][s]), a2 = red32(acc[2][s]);
            hp[s] = gru1(gp[1][s][0], gp[1][s][1], gp[1][s][2], a0, a1, a2, bh, hp[s]);
        }
        if (lane == 0)
#pragma unroll
            for (int s = 0; s < 2; ++s)
                __hip_atomic_store(tr + 2048 + s * 512 + j, hp[s],
                                   __ATOMIC_RELAXED, __HIP_MEMORY_SCOPE_AGENT);
    }

    // ================= stage E: similarity head (WG0 only) =================
    if (wgi != 0) return;
    __syncthreads();                       // stage-D reads done; safe to overwrite xlds
    if (tid < 256) stage_poll(xlds, tr + 2048, tid);  // hA=[0..511], hB=[512..1023]
    __syncthreads();
    float v = 0.f;
    if (tid < 256) {
        float acc = b_bi[tid];
        for (int jj = 0; jj < 512; ++jj) {
            const float a = xlds[LDSP(jj)];
            const float b = xlds[LDSP(512 + jj)];
            acc += (a * b) * WA[(size_t)jj * 256 + tid]
                 + fabsf(a - b) * WB[(size_t)jj * 256 + tid];
        }
        v = tanhf(acc) * Wlin[tid];
    }
    v += __shfl_xor(v, 32, 64);
    v += __shfl_xor(v, 16, 64);
    v += __shfl_xor(v, 8, 64);
    v += __shfl_xor(v, 4, 64);
    v += __shfl_xor(v, 2, 64);
    v += __shfl_xor(v, 1, 64);
    if ((tid & 63) == 0) red[tid >> 6] = v;
    __syncthreads();
    if (tid == 0) {
        float ssum = blin[0];
        for (int i = 0; i < 8; ++i) ssum += red[i];
        outp[0] = 1.f / (1.f + expf(-ssum));
    }
}

// ---------------------------------------------------------------------------
// gi GEMM (L0 only): out[m][n] = sum_k A[m][k]*W[n][k] + bias[n]  (unchanged)
// ---------------------------------------------------------------------------
__global__ __launch_bounds__(256, 2) void k_gemm_gi(
    const float* __restrict__ W, const float* __restrict__ bias,
    const float* __restrict__ emb, const int* __restrict__ sentA,
    const int* __restrict__ sentB, float* __restrict__ out)
{
    __shared__ float At[32][68];
    __shared__ float Wt[32][68];
    const int tid = threadIdx.x;
    const int n0 = blockIdx.x * 64;
    const int m0 = blockIdx.y * 64;
    const int lrow = tid >> 3, lc4 = tid & 7;

    const int ma = m0 + lrow, mb = ma + 32;
    const int ia = (ma < 256) ? sentA[ma & 255] : sentB[ma & 255];
    const int ib = (mb < 256) ? sentA[mb & 255] : sentB[mb & 255];
    const float* ar0 = emb + (size_t)ia * 512;
    const float* ar1 = emb + (size_t)ib * 512;
    const float* wr0 = W + (size_t)(n0 + lrow) * 512;
    const float* wr1 = wr0 + (size_t)32 * 512;

    const int ty = tid >> 4, tx = tid & 15;
    float acc[4][4];
#pragma unroll
    for (int i = 0; i < 4; ++i)
#pragma unroll
        for (int jj = 0; jj < 4; ++jj) acc[i][jj] = 0.f;

    for (int kk = 0; kk < 512; kk += 32) {
        float4 a0 = *(const float4*)(ar0 + kk + lc4 * 4);
        float4 a1 = *(const float4*)(ar1 + kk + lc4 * 4);
        float4 w0 = *(const float4*)(wr0 + kk + lc4 * 4);
        float4 w1 = *(const float4*)(wr1 + kk + lc4 * 4);
        __syncthreads();
        const int kb = lc4 * 4;
        At[kb+0][lrow] = a0.x; At[kb+1][lrow] = a0.y; At[kb+2][lrow] = a0.z; At[kb+3][lrow] = a0.w;
        At[kb+0][lrow+32] = a1.x; At[kb+1][lrow+32] = a1.y; At[kb+2][lrow+32] = a1.z; At[kb+3][lrow+32] = a1.w;
        Wt[kb+0][lrow] = w0.x; Wt[kb+1][lrow] = w0.y; Wt[kb+2][lrow] = w0.z; Wt[kb+3][lrow] = w0.w;
        Wt[kb+0][lrow+32] = w1.x; Wt[kb+1][lrow+32] = w1.y; Wt[kb+2][lrow+32] = w1.z; Wt[kb+3][lrow+32] = w1.w;
        __syncthreads();
#pragma unroll
        for (int k = 0; k < 32; ++k) {
            float4 av = *(const float4*)&At[k][ty * 4];
            float4 wv = *(const float4*)&Wt[k][tx * 4];
            acc[0][0] += av.x * wv.x; acc[0][1] += av.x * wv.y; acc[0][2] += av.x * wv.z; acc[0][3] += av.x * wv.w;
            acc[1][0] += av.y * wv.x; acc[1][1] += av.y * wv.y; acc[1][2] += av.y * wv.z; acc[1][3] += av.y * wv.w;
            acc[2][0] += av.z * wv.x; acc[2][1] += av.z * wv.y; acc[2][2] += av.z * wv.z; acc[2][3] += av.z * wv.w;
            acc[3][0] += av.w * wv.x; acc[3][1] += av.w * wv.y; acc[3][2] += av.w * wv.z; acc[3][3] += av.w * wv.w;
        }
    }
    float4 b4 = *(const float4*)(bias + n0 + tx * 4);
#pragma unroll
    for (int i = 0; i < 4; ++i) {
        const int m = m0 + ty * 4 + i;
        float4 r;
        r.x = acc[i][0] + b4.x; r.y = acc[i][1] + b4.y;
        r.z = acc[i][2] + b4.z; r.w = acc[i][3] + b4.w;
        *(float4*)(out + (size_t)m * 1536 + n0 + tx * 4) = r;
    }
}

// ---------------------------------------------------------------------------
// init: zero mf; poison hbuf0/hbuf1 (t=1..256) + tb0/tb1/tr (steps 1..2);
// Srow[r] = sum_k Wih2[r][k] (k<128). Re-poison runs every launch (graph-safe).
// ---------------------------------------------------------------------------
__global__ __launch_bounds__(256) void k_init(
    const float* __restrict__ Wih2, float* __restrict__ Srow,
    unsigned int* __restrict__ mf,
    unsigned int* __restrict__ hb0, unsigned int* __restrict__ hb1,
    unsigned int* __restrict__ tb0u, unsigned int* __restrict__ tb1u,
    unsigned int* __restrict__ tru)
{
    const int g = blockIdx.x * 256 + threadIdx.x;
    if (g < 1536) {
        float s = 0.f;
        for (int k = 0; k < 128; ++k) s += Wih2[(size_t)g * 128 + k];
        Srow[g] = s;
    }
    if (g < 16) mf[g] = 0u;
    if (g < 2048) {
        tb0u[1024 + g] = CANARY_U;
        tb1u[1024 + g] = CANARY_U;
        tru[1024 + g]  = CANARY_U;
    }
    const int N = 256 * 1024;                 // words per hbuf, t=1..256
    const int stride = gridDim.x * 256;
    for (int i = g; i < N; i += stride) {
        hb0[1024 + i] = CANARY_U;
        hb1[1024 + i] = CANARY_U;
    }
}

// ---------------------------------------------------------------------------
extern "C" void kernel_launch(void* const* d_in, const int* in_sizes, int n_in,
                              void* d_out, int out_size, void* d_ws, size_t ws_size,
                              hipStream_t stream)
{
    const int*   sentA = (const int*)d_in[0];
    const int*   sentB = (const int*)d_in[1];
    const float* emb   = (const float*)d_in[2];
    const float* Wih1  = (const float*)d_in[3];   // [2][1536][512]
    const float* Whh1  = (const float*)d_in[4];   // [2][1536][512]
    const float* bih1  = (const float*)d_in[5];   // [2][1536]
    const float* bhh1  = (const float*)d_in[6];   // [2][1536]
    const float* convw = (const float*)d_in[7];   // [2][2][512]
    const float* convb = (const float*)d_in[8];   // [2]
    const float* Wih2  = (const float*)d_in[9];   // [1536][128]
    const float* Whh2  = (const float*)d_in[10];  // [1536][512]
    const float* bih2  = (const float*)d_in[11];  // [1536]
    const float* bhh2  = (const float*)d_in[12];  // [1536]
    const float* WA    = (const float*)d_in[13];  // [512][256]
    const float* WB    = (const float*)d_in[14];  // [512][256]
    const float* b_bi  = (const float*)d_in[15];  // [256]
    const float* Wlin  = (const float*)d_in[16];  // [1][256]
    const float* blin  = (const float*)d_in[17];  // [1]

    float* ws = (float*)d_ws;
    size_t off = 0;
    float* gi_buf = ws + off; off += 786432;      // [2][256][1536]
    float* e2x    = ws + off; off += 2048;        // [2 sent][2 layer][512]
    float* hbuf0  = ws + off; off += 257 * 1024;
    float* hbuf1  = ws + off; off += 257 * 1024;
    float* tb0    = ws + off; off += 3 * 1024;
    float* tb1    = ws + off; off += 3 * 1024;
    float* tr     = ws + off; off += 3 * 1024;
    float* Mmax   = ws + off; off += 16;
    float* Srow   = ws + off; off += 1536;
    unsigned int* flags = (unsigned int*)(ws + off);  // 1552 u32 (layout kept)
    unsigned int* mf   = flags + 1536;

    k_init<<<256, 256, 0, stream>>>(Wih2, Srow, mf,
                                    (unsigned int*)hbuf0, (unsigned int*)hbuf1,
                                    (unsigned int*)tb0, (unsigned int*)tb1,
                                    (unsigned int*)tr);

    k_gemm_gi<<<dim3(24, 8), 256, 0, stream>>>(Wih1, bih1, emb, sentA, sentB, gi_buf);

    k_pipe<<<64, 512, 0, stream>>>(Whh1, bhh1, Wih1, bih1, gi_buf,
                                   e2x, hbuf0, hbuf1);

    k_tail<<<32, 512, 0, stream>>>(Wih1, bih1, Whh1, bhh1, convw, convb,
                                   Whh2, bhh2, bih2, Srow, e2x,
                                   WA, WB, b_bi, Wlin, blin,
                                   tb0, tb1, tr, Mmax, mf, (float*)d_out);
}

// Round 4
// 1302.617 us; speedup vs baseline: 1.0585x; 1.0585x over previous
//
#include <hip/hip_runtime.h>
#include <math.h>

// ---------------------------------------------------------------------------
// Com_CNN_RNN R9 (= R7/R8 experiment, clean resubmit):
//  busy-spin data-polling (bounded hot phase), packed 8B publishes.
//  - hbuf/tb/tr layout [step][row][2 sentences]: producer half-wave lane0 does
//    ONE 8B relaxed-atomic store; consumer thread polls 16B (2 rows x 2 sent).
//  - k_tail: conv+maxpool replicated in every WG (no Mmax global sync);
//    conv weights staged to LDS; conv spread over all 512 threads.
//  - GRU outputs satisfy |h| < 1, so FLT_MAX bits are an unreachable canary.
//    k_init re-poisons all exchange buffers every launch (graph-replay safe).
// ---------------------------------------------------------------------------

#define CANARY_U 0x7F7FFFFFu   // FLT_MAX bit pattern; |GRU h| < 1 can't hit it
#define SPIN_HOT 4096          // busy-spin probes before s_sleep fallback

__device__ __forceinline__ float sigm(float x) { return 1.f / (1.f + expf(-x)); }

// LDS index map: p(k) = k + (k>>4)*4 (pad 4 words per 16; keeps float4 align)
#define LDSP(k) ((k) + (((k) >> 4) << 2))

__device__ __forceinline__ float red32(float v) {
    v += __shfl_xor(v, 16, 64);
    v += __shfl_xor(v, 8, 64);
    v += __shfl_xor(v, 4, 64);
    v += __shfl_xor(v, 2, 64);
    v += __shfl_xor(v, 1, 64);
    return v;
}

// Publisher: half-wave lane0 packs h for both sentences of row j into one 8B store.
__device__ __forceinline__ void pub2(float* base, int j, float h0, float h1) {
    union { float2 f; unsigned long long u; } p;
    p.f = make_float2(h0, h1);
    __hip_atomic_store((unsigned long long*)base + j, p.u,
                       __ATOMIC_RELAXED, __HIP_MEMORY_SCOPE_AGENT);
}

// Consumer: thread i (0..255) polls rows 2i,2i+1 (x both sentences = 16B)
// of src (layout [512 rows][2 sent]) until non-canary, then scatters to LDS
// in [sent][row] order (LDSP-padded). Caller barriers afterwards.
__device__ __forceinline__ void stage_pollx2(float* dst, const float* src, int i) {
    const unsigned long long* s = (const unsigned long long*)src + (size_t)i * 2;
    unsigned long long a, b;
    int spins = 0;
    for (;;) {
        a = __hip_atomic_load(s + 0, __ATOMIC_RELAXED, __HIP_MEMORY_SCOPE_AGENT);
        b = __hip_atomic_load(s + 1, __ATOMIC_RELAXED, __HIP_MEMORY_SCOPE_AGENT);
        if ((unsigned int)a != CANARY_U && (unsigned int)(a >> 32) != CANARY_U &&
            (unsigned int)b != CANARY_U && (unsigned int)(b >> 32) != CANARY_U)
            break;
        if (++spins > SPIN_HOT) __builtin_amdgcn_s_sleep(1);  // watchdog hedge
    }
    union { unsigned long long u; float2 f; } c0, c1;
    c0.u = a; c1.u = b;
    const int r0 = 2 * i, r1 = 2 * i + 1;
    dst[LDSP(r0)]       = c0.f.x;
    dst[LDSP(512 + r0)] = c0.f.y;
    dst[LDSP(r1)]       = c1.f.x;
    dst[LDSP(512 + r1)] = c1.f.y;
}

__device__ __forceinline__ float gru1(float gr, float gz, float gn,
                                      float ar, float az, float an,
                                      const float bh[3], float hp) {
    float r = sigm(gr + ar + bh[0]);
    float z = sigm(gz + az + bh[1]);
    float n = tanhf(gn + r * (an + bh[2]));
    return (1.f - z) * n + z * hp;
}

// ---------------------------------------------------------------------------
// k_pipe: epoch-1 L0 + L1 pipelined, busy-poll. grid 64 x 512.
// hbuf layout: [257 steps][512 rows][2 sentences]
// ---------------------------------------------------------------------------
__global__ __launch_bounds__(512, 1) void k_pipe(
    const float* __restrict__ Whh1, const float* __restrict__ bhh1,
    const float* __restrict__ Wih1, const float* __restrict__ bih1,
    const float* __restrict__ gi0,        // [2][256][1536] (L0 only)
    float* __restrict__ e2x,              // [2 sent][2 layer][512]
    float* __restrict__ hbuf0,            // poisoned t=1..256
    float* __restrict__ hbuf1)            // poisoned t=1..256
{
    const int tid   = threadIdx.x;
    const int layer = blockIdx.x >> 5;    // 0 or 1
    const int wgi   = blockIdx.x & 31;
    const int grp   = tid >> 5;           // 0..15 (32-lane half-wave groups)
    const int lane  = tid & 31;
    const int j     = wgi * 16 + grp;     // h row 0..511
    const int colbase = lane * 16;

    __shared__ float xlds[2][1280];
    __shared__ float hlds[2][1280];

    const size_t WS = (size_t)1536 * 512;
    const float* WH = Whh1 + (size_t)layer * WS;

    float wh[3][16];
#pragma unroll
    for (int q = 0; q < 3; ++q) {
        const float* src = WH + (size_t)(q * 512 + j) * 512 + colbase;
#pragma unroll
        for (int c4 = 0; c4 < 4; ++c4) {
            float4 v = *(const float4*)(src + c4 * 4);
            wh[q][c4*4+0] = v.x; wh[q][c4*4+1] = v.y;
            wh[q][c4*4+2] = v.z; wh[q][c4*4+3] = v.w;
        }
    }
#pragma unroll
    for (int q = 0; q < 3; ++q)
#pragma unroll
        for (int c = 0; c < 16; ++c)
            asm volatile("" : "+v"(wh[q][c]));

    float bh[3];
#pragma unroll
    for (int q = 0; q < 3; ++q) bh[q] = bhh1[layer * 1536 + q * 512 + j];

    float hprev[2] = {0.f, 0.f};
    int buf = 0;

    if (layer == 0) {
        for (int t = 1; t <= 256; ++t) {
            float g0[3][2];
#pragma unroll
            for (int q = 0; q < 3; ++q)
#pragma unroll
                for (int s = 0; s < 2; ++s)
                    g0[q][s] = gi0[((size_t)(s * 256 + t - 1)) * 1536 + q * 512 + j];

            float acc[3][2] = {{0.f,0.f},{0.f,0.f},{0.f,0.f}};
            if (t > 1) {
                if (tid < 256)
                    stage_pollx2(xlds[buf], hbuf0 + (size_t)(t - 1) * 1024, tid);
                __syncthreads();
#pragma unroll
                for (int s = 0; s < 2; ++s) {
                    const int base = s * 640 + 20 * lane;
#pragma unroll
                    for (int c4 = 0; c4 < 4; ++c4) {
                        float4 hv = *(const float4*)&xlds[buf][base + c4 * 4];
#pragma unroll
                        for (int q = 0; q < 3; ++q)
                            acc[q][s] += wh[q][c4*4+0]*hv.x + wh[q][c4*4+1]*hv.y
                                       + wh[q][c4*4+2]*hv.z + wh[q][c4*4+3]*hv.w;
                    }
                }
#pragma unroll
                for (int q = 0; q < 3; ++q)
#pragma unroll
                    for (int s = 0; s < 2; ++s) acc[q][s] = red32(acc[q][s]);
            }

            float hn[2];
#pragma unroll
            for (int s = 0; s < 2; ++s) {
                hn[s] = gru1(g0[0][s], g0[1][s], g0[2][s],
                             acc[0][s], acc[1][s], acc[2][s], bh, hprev[s]);
                hprev[s] = hn[s];
            }
            if (lane == 0) {
                pub2(hbuf0 + (size_t)t * 1024, j, hn[0], hn[1]);
                if (t == 256)
#pragma unroll
                    for (int s = 0; s < 2; ++s) e2x[s * 1024 + j] = hn[s];
            }
            buf ^= 1;
        }
    } else {
        const float* WI = Wih1 + WS;
        float wi[3][16];
#pragma unroll
        for (int q = 0; q < 3; ++q) {
            const float* src = WI + (size_t)(q * 512 + j) * 512 + colbase;
#pragma unroll
            for (int c4 = 0; c4 < 4; ++c4) {
                float4 v = *(const float4*)(src + c4 * 4);
                wi[q][c4*4+0] = v.x; wi[q][c4*4+1] = v.y;
                wi[q][c4*4+2] = v.z; wi[q][c4*4+3] = v.w;
            }
        }
#pragma unroll
        for (int q = 0; q < 3; ++q)
#pragma unroll
            for (int c = 0; c < 16; ++c)
                asm volatile("" : "+v"(wi[q][c]));

        float bi[3];
#pragma unroll
        for (int q = 0; q < 3; ++q) bi[q] = bih1[1536 + q * 512 + j];

        for (int t = 1; t <= 256; ++t) {
            if (tid < 256)
                stage_pollx2(xlds[buf], hbuf0 + (size_t)t * 1024, tid);
            else if (t > 1)
                stage_pollx2(hlds[buf], hbuf1 + (size_t)(t - 1) * 1024, tid - 256);
            __syncthreads();

            float aR[2] = {0.f,0.f}, aZ[2] = {0.f,0.f};
            float aGN[2] = {0.f,0.f}, aHN[2] = {0.f,0.f};
#pragma unroll
            for (int s = 0; s < 2; ++s) {
                const int base = s * 640 + 20 * lane;
#pragma unroll
                for (int c4 = 0; c4 < 4; ++c4) {
                    float4 xv = *(const float4*)&xlds[buf][base + c4 * 4];
                    aR[s]  += wi[0][c4*4+0]*xv.x + wi[0][c4*4+1]*xv.y
                            + wi[0][c4*4+2]*xv.z + wi[0][c4*4+3]*xv.w;
                    aZ[s]  += wi[1][c4*4+0]*xv.x + wi[1][c4*4+1]*xv.y
                            + wi[1][c4*4+2]*xv.z + wi[1][c4*4+3]*xv.w;
                    aGN[s] += wi[2][c4*4+0]*xv.x + wi[2][c4*4+1]*xv.y
                            + wi[2][c4*4+2]*xv.z + wi[2][c4*4+3]*xv.w;
                }
                if (t > 1) {
#pragma unroll
                    for (int c4 = 0; c4 < 4; ++c4) {
                        float4 hv = *(const float4*)&hlds[buf][base + c4 * 4];
                        aR[s]  += wh[0][c4*4+0]*hv.x + wh[0][c4*4+1]*hv.y
                                + wh[0][c4*4+2]*hv.z + wh[0][c4*4+3]*hv.w;
                        aZ[s]  += wh[1][c4*4+0]*hv.x + wh[1][c4*4+1]*hv.y
                                + wh[1][c4*4+2]*hv.z + wh[1][c4*4+3]*hv.w;
                        aHN[s] += wh[2][c4*4+0]*hv.x + wh[2][c4*4+1]*hv.y
                                + wh[2][c4*4+2]*hv.z + wh[2][c4*4+3]*hv.w;
                    }
                }
            }
#pragma unroll
            for (int s = 0; s < 2; ++s) {
                aR[s] = red32(aR[s]); aZ[s] = red32(aZ[s]);
                aGN[s] = red32(aGN[s]); aHN[s] = red32(aHN[s]);
            }

            float hn[2];
#pragma unroll
            for (int s = 0; s < 2; ++s) {
                float r = sigm(aR[s] + bi[0] + bh[0]);
                float z = sigm(aZ[s] + bi[1] + bh[1]);
                float n = tanhf(aGN[s] + bi[2] + r * (aHN[s] + bh[2]));
                hn[s] = (1.f - z) * n + z * hprev[s];
                hprev[s] = hn[s];
            }
            if (lane == 0) {
                pub2(hbuf1 + (size_t)t * 1024, j, hn[0], hn[1]);
                if (t == 256)
#pragma unroll
                    for (int s = 0; s < 2; ++s) e2x[s * 1024 + 512 + j] = hn[s];
            }
            buf ^= 1;
        }
    }
}

// ---------------------------------------------------------------------------
// k_tail: e2-L0 -> e2-L1 -> conv+pool (replicated) -> rnn2 -> head. 32 x 512.
// tb/tr layout: [3 steps][512 rows][2 sentences]
// ---------------------------------------------------------------------------
__global__ __launch_bounds__(512, 1) void k_tail(
    const float* __restrict__ Wih1, const float* __restrict__ bih1,
    const float* __restrict__ Whh1, const float* __restrict__ bhh1,
    const float* __restrict__ convw, const float* __restrict__ convb,
    const float* __restrict__ Whh2, const float* __restrict__ bhh2,
    const float* __restrict__ bih2, const float* __restrict__ Srow,
    const float* __restrict__ e2x,
    const float* __restrict__ WA, const float* __restrict__ WB,
    const float* __restrict__ b_bi, const float* __restrict__ Wlin,
    const float* __restrict__ blin,
    float* __restrict__ tb0, float* __restrict__ tb1, float* __restrict__ tr,
    float* __restrict__ outp)
{
    const int tid = threadIdx.x;
    const int wgi = blockIdx.x;
    const int grp = tid >> 5, lane = tid & 31;
    const int j = wgi * 16 + grp, colbase = lane * 16;
    const size_t WS = (size_t)1536 * 512;

    __shared__ float xlds[1280];
    __shared__ float hlds[1280];
    __shared__ float cwlds[2048];
    __shared__ float part[16];
    __shared__ float red[8];
    __shared__ float smax[4];

    // stage e2x into LDS (plain loads; written by previous dispatch)
    if (tid < 256) {
        const int i = tid * 4, s = i >> 9, k = i & 511;
        float4 v = *(const float4*)(e2x + s * 1024 + k);        // timestep 0
        float* d = xlds + LDSP(i);
        d[0] = v.x; d[1] = v.y; d[2] = v.z; d[3] = v.w;
    } else {
        const int i = (tid - 256) * 4, s = i >> 9, k = i & 511;
        float4 v = *(const float4*)(e2x + s * 1024 + 512 + k);  // timestep 1
        float* d = hlds + LDSP(i);
        d[0] = v.x; d[1] = v.y; d[2] = v.z; d[3] = v.w;
    }
    __syncthreads();

    // ================= stage A: e2-L0 =================
    float gp[2][2][3];
    float bh[3], hp[2];
#pragma unroll
    for (int q = 0; q < 3; ++q) {
        const float* wp = Wih1 + (size_t)(q * 512 + j) * 512 + colbase;
        float w16[16];
#pragma unroll
        for (int c4 = 0; c4 < 4; ++c4) {
            float4 v = *(const float4*)(wp + c4 * 4);
            w16[c4*4+0] = v.x; w16[c4*4+1] = v.y; w16[c4*4+2] = v.z; w16[c4*4+3] = v.w;
        }
        float d00 = 0.f, d01 = 0.f, d10 = 0.f, d11 = 0.f;
#pragma unroll
        for (int c4 = 0; c4 < 4; ++c4) {
            float4 x0 = *(const float4*)&xlds[0 * 640 + 20 * lane + c4 * 4];
            float4 x1 = *(const float4*)&xlds[1 * 640 + 20 * lane + c4 * 4];
            float4 y0 = *(const float4*)&hlds[0 * 640 + 20 * lane + c4 * 4];
            float4 y1 = *(const float4*)&hlds[1 * 640 + 20 * lane + c4 * 4];
            d00 += w16[c4*4+0]*x0.x + w16[c4*4+1]*x0.y + w16[c4*4+2]*x0.z + w16[c4*4+3]*x0.w;
            d01 += w16[c4*4+0]*x1.x + w16[c4*4+1]*x1.y + w16[c4*4+2]*x1.z + w16[c4*4+3]*x1.w;
            d10 += w16[c4*4+0]*y0.x + w16[c4*4+1]*y0.y + w16[c4*4+2]*y0.z + w16[c4*4+3]*y0.w;
            d11 += w16[c4*4+0]*y1.x + w16[c4*4+1]*y1.y + w16[c4*4+2]*y1.z + w16[c4*4+3]*y1.w;
        }
        const float biq = bih1[q * 512 + j];
        gp[0][0][q] = red32(d00) + biq; gp[0][1][q] = red32(d01) + biq;
        gp[1][0][q] = red32(d10) + biq; gp[1][1][q] = red32(d11) + biq;
    }
#pragma unroll
    for (int q = 0; q < 3; ++q) bh[q] = bhh1[q * 512 + j];

#pragma unroll
    for (int s = 0; s < 2; ++s)
        hp[s] = gru1(gp[0][s][0], gp[0][s][1], gp[0][s][2], 0.f, 0.f, 0.f, bh, 0.f);
    if (lane == 0) pub2(tb0 + 1024, j, hp[0], hp[1]);

    __syncthreads();
    if (tid < 256) stage_pollx2(hlds, tb0 + 1024, tid);
    __syncthreads();
    {
        float wh3[3][16];
#pragma unroll
        for (int q = 0; q < 3; ++q) {
            const float* wp = Whh1 + (size_t)(q * 512 + j) * 512 + colbase;
#pragma unroll
            for (int c4 = 0; c4 < 4; ++c4) {
                float4 v = *(const float4*)(wp + c4 * 4);
                wh3[q][c4*4+0] = v.x; wh3[q][c4*4+1] = v.y;
                wh3[q][c4*4+2] = v.z; wh3[q][c4*4+3] = v.w;
            }
        }
        float acc[3][2] = {{0.f,0.f},{0.f,0.f},{0.f,0.f}};
#pragma unroll
        for (int s = 0; s < 2; ++s) {
            const int base = s * 640 + 20 * lane;
#pragma unroll
            for (int c4 = 0; c4 < 4; ++c4) {
                float4 hv = *(const float4*)&hlds[base + c4 * 4];
#pragma unroll
                for (int q = 0; q < 3; ++q)
                    acc[q][s] += wh3[q][c4*4+0]*hv.x + wh3[q][c4*4+1]*hv.y
                               + wh3[q][c4*4+2]*hv.z + wh3[q][c4*4+3]*hv.w;
            }
        }
#pragma unroll
        for (int s = 0; s < 2; ++s) {
            float a0 = red32(acc[0][s]), a1 = red32(acc[1][s]), a2 = red32(acc[2][s]);
            hp[s] = gru1(gp[1][s][0], gp[1][s][1], gp[1][s][2], a0, a1, a2, bh, hp[s]);
        }
        if (lane == 0) pub2(tb0 + 2048, j, hp[0], hp[1]);
    }

    // ================= stage B: e2-L1 =================
    __syncthreads();
    if (tid < 256) stage_pollx2(xlds, tb0 + 1024, tid);
    else           stage_pollx2(hlds, tb0 + 2048, tid - 256);
    __syncthreads();
#pragma unroll
    for (int q = 0; q < 3; ++q) {
        const float* wp = Wih1 + WS + (size_t)(q * 512 + j) * 512 + colbase;
        float w16[16];
#pragma unroll
        for (int c4 = 0; c4 < 4; ++c4) {
            float4 v = *(const float4*)(wp + c4 * 4);
            w16[c4*4+0] = v.x; w16[c4*4+1] = v.y; w16[c4*4+2] = v.z; w16[c4*4+3] = v.w;
        }
        float d00 = 0.f, d01 = 0.f, d10 = 0.f, d11 = 0.f;
#pragma unroll
        for (int c4 = 0; c4 < 4; ++c4) {
            float4 x0 = *(const float4*)&xlds[0 * 640 + 20 * lane + c4 * 4];
            float4 x1 = *(const float4*)&xlds[1 * 640 + 20 * lane + c4 * 4];
            float4 y0 = *(const float4*)&hlds[0 * 640 + 20 * lane + c4 * 4];
            float4 y1 = *(const float4*)&hlds[1 * 640 + 20 * lane + c4 * 4];
            d00 += w16[c4*4+0]*x0.x + w16[c4*4+1]*x0.y + w16[c4*4+2]*x0.z + w16[c4*4+3]*x0.w;
            d01 += w16[c4*4+0]*x1.x + w16[c4*4+1]*x1.y + w16[c4*4+2]*x1.z + w16[c4*4+3]*x1.w;
            d10 += w16[c4*4+0]*y0.x + w16[c4*4+1]*y0.y + w16[c4*4+2]*y0.z + w16[c4*4+3]*y0.w;
            d11 += w16[c4*4+0]*y1.x + w16[c4*4+1]*y1.y + w16[c4*4+2]*y1.z + w16[c4*4+3]*y1.w;
        }
        const float biq = bih1[1536 + q * 512 + j];
        gp[0][0][q] = red32(d00) + biq; gp[0][1][q] = red32(d01) + biq;
        gp[1][0][q] = red32(d10) + biq; gp[1][1][q] = red32(d11) + biq;
    }
#pragma unroll
    for (int q = 0; q < 3; ++q) bh[q] = bhh1[1536 + q * 512 + j];

#pragma unroll
    for (int s = 0; s < 2; ++s)
        hp[s] = gru1(gp[0][s][0], gp[0][s][1], gp[0][s][2], 0.f, 0.f, 0.f, bh, 0.f);
    if (lane == 0) pub2(tb1 + 1024, j, hp[0], hp[1]);

    __syncthreads();
    if (tid < 256) stage_pollx2(hlds, tb1 + 1024, tid);
    __syncthreads();
    {
        float wh3[3][16];
#pragma unroll
        for (int q = 0; q < 3; ++q) {
            const float* wp = Whh1 + WS + (size_t)(q * 512 + j) * 512 + colbase;
#pragma unroll
            for (int c4 = 0; c4 < 4; ++c4) {
                float4 v = *(const float4*)(wp + c4 * 4);
                wh3[q][c4*4+0] = v.x; wh3[q][c4*4+1] = v.y;
                wh3[q][c4*4+2] = v.z; wh3[q][c4*4+3] = v.w;
            }
        }
        float acc[3][2] = {{0.f,0.f},{0.f,0.f},{0.f,0.f}};
#pragma unroll
        for (int s = 0; s < 2; ++s) {
            const int base = s * 640 + 20 * lane;
#pragma unroll
            for (int c4 = 0; c4 < 4; ++c4) {
                float4 hv = *(const float4*)&hlds[base + c4 * 4];
#pragma unroll
                for (int q = 0; q < 3; ++q)
                    acc[q][s] += wh3[q][c4*4+0]*hv.x + wh3[q][c4*4+1]*hv.y
                               + wh3[q][c4*4+2]*hv.z + wh3[q][c4*4+3]*hv.w;
            }
        }
#pragma unroll
        for (int s = 0; s < 2; ++s) {
            float a0 = red32(acc[0][s]), a1 = red32(acc[1][s]), a2 = red32(acc[2][s]);
            hp[s] = gru1(gp[1][s][0], gp[1][s][1], gp[1][s][2], a0, a1, a2, bh, hp[s]);
        }
        if (lane == 0) pub2(tb1 + 2048, j, hp[0], hp[1]);
    }

    // ======== stage C: conv + global max pool (replicated in every WG) ========
    __syncthreads();
    if (tid < 256) {
        stage_pollx2(xlds, tb0 + 2048, tid);        // finals L0 [s][512]
        const int b8 = tid * 8;
#pragma unroll
        for (int u = 0; u < 8; ++u) cwlds[b8 + u] = convw[b8 + u];
    } else {
        stage_pollx2(hlds, tb1 + 2048, tid - 256);  // finals L1 [s][512]
    }
    __syncthreads();
#pragma unroll
    for (int oo = 0; oo < 2; ++oo) {
        const int w = tid + oo * 512;
        const int so = w >> 8, pos = w & 255;
        const int s = so >> 1, o = so & 1;
        float acc = convb[o];
        const int base = 2 * pos - 255;
        for (int k = 0; k < 512; ++k) {
            const int p2 = base + k;
            if ((unsigned)p2 < 512u) {
                const int gi0i = s * 512 + p2;
                acc += xlds[LDSP(gi0i)] * cwlds[(o * 2 + 0) * 512 + k]
                     + hlds[LDSP(gi0i)] * cwlds[(o * 2 + 1) * 512 + k];
            }
        }
        float m = acc;
        m = fmaxf(m, __shfl_xor(m, 32, 64));
        m = fmaxf(m, __shfl_xor(m, 16, 64));
        m = fmaxf(m, __shfl_xor(m, 8, 64));
        m = fmaxf(m, __shfl_xor(m, 4, 64));
        m = fmaxf(m, __shfl_xor(m, 2, 64));
        m = fmaxf(m, __shfl_xor(m, 1, 64));
        if ((tid & 63) == 0) part[oo * 8 + (tid >> 6)] = m;   // so uniform per wave
    }
    __syncthreads();
    if (tid < 4) {
        float mm = -3.4e38f;
        for (int p = 0; p < 16; ++p) {
            const int so_p = ((p & 7) >> 2) + 2 * (p >> 3);
            if (so_p == tid) mm = fmaxf(mm, part[p]);
        }
        smax[tid] = mm;
    }
    __syncthreads();
    float m4[4];
#pragma unroll
    for (int i = 0; i < 4; ++i) m4[i] = smax[i];

    // ================= stage D: rnn2 (T=2, gi = Mmax*Srow + bih2) =================
    {
        float wh3[3][16];
#pragma unroll
        for (int q = 0; q < 3; ++q) {
            const float* wp = Whh2 + (size_t)(q * 512 + j) * 512 + colbase;
#pragma unroll
            for (int c4 = 0; c4 < 4; ++c4) {
                float4 v = *(const float4*)(wp + c4 * 4);
                wh3[q][c4*4+0] = v.x; wh3[q][c4*4+1] = v.y;
                wh3[q][c4*4+2] = v.z; wh3[q][c4*4+3] = v.w;
            }
        }
#pragma unroll
        for (int q = 0; q < 3; ++q) {
            const float sq = Srow[q * 512 + j];
            const float biq = bih2[q * 512 + j];
#pragma unroll
            for (int s = 0; s < 2; ++s) {
                gp[0][s][q] = m4[s * 2 + 0] * sq + biq;
                gp[1][s][q] = m4[s * 2 + 1] * sq + biq;
            }
            bh[q] = bhh2[q * 512 + j];
        }
#pragma unroll
        for (int s = 0; s < 2; ++s)
            hp[s] = gru1(gp[0][s][0], gp[0][s][1], gp[0][s][2], 0.f, 0.f, 0.f, bh, 0.f);
        if (lane == 0) pub2(tr + 1024, j, hp[0], hp[1]);

        __syncthreads();                   // conv reads of hlds done
        if (tid < 256) stage_pollx2(hlds, tr + 1024, tid);
        __syncthreads();
        float acc[3][2] = {{0.f,0.f},{0.f,0.f},{0.f,0.f}};
#pragma unroll
        for (int s = 0; s < 2; ++s) {
            const int base = s * 640 + 20 * lane;
#pragma unroll
            for (int c4 = 0; c4 < 4; ++c4) {
                float4 hv = *(const float4*)&hlds[base + c4 * 4];
#pragma unroll
                for (int q = 0; q < 3; ++q)
                    acc[q][s] += wh3[q][c4*4+0]*hv.x + wh3[q][c4*4+1]*hv.y
                               + wh3[q][c4*4+2]*hv.z + wh3[q][c4*4+3]*hv.w;
            }
        }
#pragma unroll
        for (int s = 0; s < 2; ++s) {
            float a0 = red32(acc[0][s]), a1 = red32(acc[1][s]), a2 = red32(acc[2][s]);
            hp[s] = gru1(gp[1][s][0], gp[1][s][1], gp[1][s][2], a0, a1, a2, bh, hp[s]);
        }
        if (lane == 0) pub2(tr + 2048, j, hp[0], hp[1]);
    }

    // ================= stage E: similarity head (WG0 only) =================
    if (wgi != 0) return;
    __syncthreads();
    if (tid < 256) stage_pollx2(xlds, tr + 2048, tid);  // [s][512]: hA, hB
    __syncthreads();
    float v = 0.f;
    if (tid < 256) {
        float acc = b_bi[tid];
        for (int jj = 0; jj < 512; ++jj) {
            const float a = xlds[LDSP(jj)];
            const float b = xlds[LDSP(512 + jj)];
            acc += (a * b) * WA[(size_t)jj * 256 + tid]
                 + fabsf(a - b) * WB[(size_t)jj * 256 + tid];
        }
        v = tanhf(acc) * Wlin[tid];
    }
    v += __shfl_xor(v, 32, 64);
    v += __shfl_xor(v, 16, 64);
    v += __shfl_xor(v, 8, 64);
    v += __shfl_xor(v, 4, 64);
    v += __shfl_xor(v, 2, 64);
    v += __shfl_xor(v, 1, 64);
    if ((tid & 63) == 0) red[tid >> 6] = v;
    __syncthreads();
    if (tid == 0) {
        float ssum = blin[0];
        for (int i = 0; i < 8; ++i) ssum += red[i];
        outp[0] = 1.f / (1.f + expf(-ssum));
    }
}

// ---------------------------------------------------------------------------
// gi GEMM (L0 only): out[m][n] = sum_k A[m][k]*W[n][k] + bias[n]  (unchanged)
// ---------------------------------------------------------------------------
__global__ __launch_bounds__(256, 2) void k_gemm_gi(
    const float* __restrict__ W, const float* __restrict__ bias,
    const float* __restrict__ emb, const int* __restrict__ sentA,
    const int* __restrict__ sentB, float* __restrict__ out)
{
    __shared__ float At[32][68];
    __shared__ float Wt[32][68];
    const int tid = threadIdx.x;
    const int n0 = blockIdx.x * 64;
    const int m0 = blockIdx.y * 64;
    const int lrow = tid >> 3, lc4 = tid & 7;

    const int ma = m0 + lrow, mb = ma + 32;
    const int ia = (ma < 256) ? sentA[ma & 255] : sentB[ma & 255];
    const int ib = (mb < 256) ? sentA[mb & 255] : sentB[mb & 255];
    const float* ar0 = emb + (size_t)ia * 512;
    const float* ar1 = emb + (size_t)ib * 512;
    const float* wr0 = W + (size_t)(n0 + lrow) * 512;
    const float* wr1 = wr0 + (size_t)32 * 512;

    const int ty = tid >> 4, tx = tid & 15;
    float acc[4][4];
#pragma unroll
    for (int i = 0; i < 4; ++i)
#pragma unroll
        for (int jj = 0; jj < 4; ++jj) acc[i][jj] = 0.f;

    for (int kk = 0; kk < 512; kk += 32) {
        float4 a0 = *(const float4*)(ar0 + kk + lc4 * 4);
        float4 a1 = *(const float4*)(ar1 + kk + lc4 * 4);
        float4 w0 = *(const float4*)(wr0 + kk + lc4 * 4);
        float4 w1 = *(const float4*)(wr1 + kk + lc4 * 4);
        __syncthreads();
        const int kb = lc4 * 4;
        At[kb+0][lrow] = a0.x; At[kb+1][lrow] = a0.y; At[kb+2][lrow] = a0.z; At[kb+3][lrow] = a0.w;
        At[kb+0][lrow+32] = a1.x; At[kb+1][lrow+32] = a1.y; At[kb+2][lrow+32] = a1.z; At[kb+3][lrow+32] = a1.w;
        Wt[kb+0][lrow] = w0.x; Wt[kb+1][lrow] = w0.y; Wt[kb+2][lrow] = w0.z; Wt[kb+3][lrow] = w0.w;
        Wt[kb+0][lrow+32] = w1.x; Wt[kb+1][lrow+32] = w1.y; Wt[kb+2][lrow+32] = w1.z; Wt[kb+3][lrow+32] = w1.w;
        __syncthreads();
#pragma unroll
        for (int k = 0; k < 32; ++k) {
            float4 av = *(const float4*)&At[k][ty * 4];
            float4 wv = *(const float4*)&Wt[k][tx * 4];
            acc[0][0] += av.x * wv.x; acc[0][1] += av.x * wv.y; acc[0][2] += av.x * wv.z; acc[0][3] += av.x * wv.w;
            acc[1][0] += av.y * wv.x; acc[1][1] += av.y * wv.y; acc[1][2] += av.y * wv.z; acc[1][3] += av.y * wv.w;
            acc[2][0] += av.z * wv.x; acc[2][1] += av.z * wv.y; acc[2][2] += av.z * wv.z; acc[2][3] += av.z * wv.w;
            acc[3][0] += av.w * wv.x; acc[3][1] += av.w * wv.y; acc[3][2] += av.w * wv.z; acc[3][3] += av.w * wv.w;
        }
    }
    float4 b4 = *(const float4*)(bias + n0 + tx * 4);
#pragma unroll
    for (int i = 0; i < 4; ++i) {
        const int m = m0 + ty * 4 + i;
        float4 r;
        r.x = acc[i][0] + b4.x; r.y = acc[i][1] + b4.y;
        r.z = acc[i][2] + b4.z; r.w = acc[i][3] + b4.w;
        *(float4*)(out + (size_t)m * 1536 + n0 + tx * 4) = r;
    }
}

// ---------------------------------------------------------------------------
// init: poison hbuf0/hbuf1 (t=1..256) + tb0/tb1/tr (steps 1..2);
// Srow[r] = sum_k Wih2[r][k] (k<128). Re-poison runs every launch (graph-safe).
// ---------------------------------------------------------------------------
__global__ __launch_bounds__(256) void k_init(
    const float* __restrict__ Wih2, float* __restrict__ Srow,
    unsigned int* __restrict__ hb0, unsigned int* __restrict__ hb1,
    unsigned int* __restrict__ tb0u, unsigned int* __restrict__ tb1u,
    unsigned int* __restrict__ tru)
{
    const int g = blockIdx.x * 256 + threadIdx.x;
    if (g < 1536) {
        float s = 0.f;
        for (int k = 0; k < 128; ++k) s += Wih2[(size_t)g * 128 + k];
        Srow[g] = s;
    }
    if (g < 2048) {
        tb0u[1024 + g] = CANARY_U;
        tb1u[1024 + g] = CANARY_U;
        tru[1024 + g]  = CANARY_U;
    }
    const int N = 256 * 1024;                 // words per hbuf, t=1..256
    const int stride = gridDim.x * 256;
    for (int i = g; i < N; i += stride) {
        hb0[1024 + i] = CANARY_U;
        hb1[1024 + i] = CANARY_U;
    }
}

// ---------------------------------------------------------------------------
extern "C" void kernel_launch(void* const* d_in, const int* in_sizes, int n_in,
                              void* d_out, int out_size, void* d_ws, size_t ws_size,
                              hipStream_t stream)
{
    const int*   sentA = (const int*)d_in[0];
    const int*   sentB = (const int*)d_in[1];
    const float* emb   = (const float*)d_in[2];
    const float* Wih1  = (const float*)d_in[3];   // [2][1536][512]
    const float* Whh1  = (const float*)d_in[4];   // [2][1536][512]
    const float* bih1  = (const float*)d_in[5];   // [2][1536]
    const float* bhh1  = (const float*)d_in[6];   // [2][1536]
    const float* convw = (const float*)d_in[7];   // [2][2][512]
    const float* convb = (const float*)d_in[8];   // [2]
    const float* Wih2  = (const float*)d_in[9];   // [1536][128]
    const float* Whh2  = (const float*)d_in[10];  // [1536][512]
    const float* bih2  = (const float*)d_in[11];  // [1536]
    const float* bhh2  = (const float*)d_in[12];  // [1536]
    const float* WA    = (const float*)d_in[13];  // [512][256]
    const float* WB    = (const float*)d_in[14];  // [512][256]
    const float* b_bi  = (const float*)d_in[15];  // [256]
    const float* Wlin  = (const float*)d_in[16];  // [1][256]
    const float* blin  = (const float*)d_in[17];  // [1]

    float* ws = (float*)d_ws;
    size_t off = 0;
    float* gi_buf = ws + off; off += 786432;      // [2][256][1536]
    float* e2x    = ws + off; off += 2048;        // [2 sent][2 layer][512]
    float* hbuf0  = ws + off; off += 257 * 1024;  // [257][512][2]
    float* hbuf1  = ws + off; off += 257 * 1024;  // [257][512][2]
    float* tb0    = ws + off; off += 3 * 1024;    // [3][512][2]
    float* tb1    = ws + off; off += 3 * 1024;
    float* tr     = ws + off; off += 3 * 1024;
    float* Srow   = ws + off; off += 1536;

    k_init<<<256, 256, 0, stream>>>(Wih2, Srow,
                                    (unsigned int*)hbuf0, (unsigned int*)hbuf1,
                                    (unsigned int*)tb0, (unsigned int*)tb1,
                                    (unsigned int*)tr);

    k_gemm_gi<<<dim3(24, 8), 256, 0, stream>>>(Wih1, bih1, emb, sentA, sentB, gi_buf);

    k_pipe<<<64, 512, 0, stream>>>(Whh1, bhh1, Wih1, bih1, gi_buf,
                                   e2x, hbuf0, hbuf1);

    k_tail<<<32, 512, 0, stream>>>(Wih1, bih1, Whh1, bhh1, convw, convb,
                                   Whh2, bhh2, bih2, Srow, e2x,
                                   WA, WB, b_bi, Wlin, blin,
                                   tb0, tb1, tr, (float*)d_out);
}